// Round 2
// baseline (398.847 us; speedup 1.0000x reference)
//
#include <hip/hip_runtime.h>

typedef __attribute__((ext_vector_type(4))) float f32x4;
typedef __attribute__((ext_vector_type(8))) short s16x8;
typedef __attribute__((ext_vector_type(4))) short s16x4;
typedef unsigned short u16;

#define T_SEQ 2048
#define EMB   2048
#define NHEAD 16
#define G32   32
#define DH    64
#define DV    128
#define NEGV  (-1e9f)
// LAMBDA_INIT = 0.8 - 0.6*exp(-0.3*12)
#define LAMBDA_INIT 0.7836057665316245f
#define SCALING 0.125f

__device__ __forceinline__ u16 f2bf(float f) {
    unsigned int u = __builtin_bit_cast(unsigned int, f);
    unsigned int r = (u + 0x7fffu + ((u >> 16) & 1u)) >> 16;
    return (u16)r;
}
__device__ __forceinline__ float bf2f(unsigned int u) {
    return __builtin_bit_cast(float, u << 16);
}
__device__ __forceinline__ void load16(const u16* g, u16* l) {
    __builtin_amdgcn_global_load_lds(
        (const __attribute__((address_space(1))) unsigned int*)g,
        (__attribute__((address_space(3))) unsigned int*)l, 16, 0, 0);
}

// ---------------- lambda scalar ----------------
__global__ void k_lambda(const float* lq1, const float* lk1,
                         const float* lq2, const float* lk2, float* lam) {
    int l = threadIdx.x;  // 64
    float a = lq1[l] * lk1[l];
    float b = lq2[l] * lk2[l];
    for (int m = 32; m; m >>= 1) { a += __shfl_xor(a, m); b += __shfl_xor(b, m); }
    if (l == 0) *lam = __expf(a) - __expf(b) + LAMBDA_INIT;
}

// ---------------- rope tables (2048 x 32) ----------------
__global__ void k_ropetab(float* cost, float* sint) {
    int i = blockIdx.x * 256 + threadIdx.x;  // 65536
    int j = i & 31, t = i >> 5;
    double invf = exp(-(double)j * (9.210340371976184 / 32.0));  // 10000^(-j/32)
    double fr = (double)t * invf;
    cost[i] = (float)cos(fr);
    sint[i] = (float)sin(fr);
}

// ---------------- x fp32 -> bf16 ----------------
__global__ void k_cvt_x(const float* __restrict__ in, u16* __restrict__ out) {
    int i = blockIdx.x * 256 + threadIdx.x;  // one per 4 elems
    f32x4 v = *(const f32x4*)(in + (size_t)i * 4);
    s16x4 o;
    for (int j = 0; j < 4; j++) o[j] = (short)f2bf(v[j]);
    *(s16x4*)(out + (size_t)i * 4) = o;
}

// ---------------- 2048x2048 fp32 -> transposed bf16 ----------------
__global__ __launch_bounds__(256)
void k_transpose_cvt(const float* __restrict__ in, u16* __restrict__ out) {
    __shared__ float tile[32][33];
    int lc = threadIdx.x & 31;
    int lr0 = (threadIdx.x >> 5) * 4;
    int col = blockIdx.x * 32 + lc;
    int row0 = blockIdx.y * 32 + lr0;
    for (int r = 0; r < 4; r++)
        tile[lr0 + r][lc] = in[(size_t)(row0 + r) * 2048 + col];
    __syncthreads();
    int ncol = blockIdx.y * 32 + lc;
    int nrow0 = blockIdx.x * 32 + lr0;
    for (int r = 0; r < 4; r++)
        out[(size_t)(nrow0 + r) * 2048 + ncol] = f2bf(tile[lc][lr0 + r]);
}

// ---------------- GEMM: C(2048x2048) = A(bf16,row) @ Bt(bf16, n-major)^T ------
// m97 recipe: global_load_lds width=16, linear LDS.
// MODE 0: write fp32 C.  MODE 1: rope+scale -> bf16 (g,t,d).  MODE 2: rope -> bf16.
template <int MODE>
__global__ __launch_bounds__(256)
void k_gemm(const u16* __restrict__ A, const u16* __restrict__ Bt,
            float* __restrict__ Cf, u16* __restrict__ Cb,
            const float* __restrict__ costab, const float* __restrict__ sintab) {
    __shared__ u16 As[128 * 32];
    __shared__ u16 Bs[128 * 32];
    int t0 = blockIdx.y * 128, n0 = blockIdx.x * 128;
    int tid = threadIdx.x;
    int lane = tid & 63, wid = tid >> 6;
    int wm = wid >> 1, wn = wid & 1;
    int rl = lane & 15, rg = lane >> 4;
    int lrow = lane >> 2, lcol = (lane & 3) * 8;   // lane*16B = lrow*64 + lcol*2
    f32x4 acc[4][4] = {};
    for (int k0 = 0; k0 < 2048; k0 += 32) {
        __syncthreads();
        for (int j = 0; j < 2; j++) {
            int row = (wid * 2 + j) * 16 + lrow;
            load16(A  + (size_t)(t0 + row) * 2048 + k0 + lcol, &As[row * 32 + lcol]);
            load16(Bt + (size_t)(n0 + row) * 2048 + k0 + lcol, &Bs[row * 32 + lcol]);
        }
        __syncthreads();
        s16x8 af[4], bfr[4];
        for (int i = 0; i < 4; i++) af[i]  = *(const s16x8*)&As[(wm * 64 + i * 16 + rl) * 32 + rg * 8];
        for (int j = 0; j < 4; j++) bfr[j] = *(const s16x8*)&Bs[(wn * 64 + j * 16 + rl) * 32 + rg * 8];
        for (int i = 0; i < 4; i++)
            for (int j = 0; j < 4; j++)
                acc[i][j] = __builtin_amdgcn_mfma_f32_16x16x32_bf16(af[i], bfr[j], acc[i][j], 0, 0, 0);
    }
    // epilogue
    for (int i = 0; i < 4; i++) {
        int trow = t0 + wm * 64 + i * 16 + rg * 4;
        for (int j = 0; j < 4; j++) {
            int col = n0 + wn * 64 + j * 16 + rl;
            if (MODE == 0) {
                for (int r = 0; r < 4; r++)
                    Cf[(size_t)(trow + r) * 2048 + col] = acc[i][j][r];
            } else {
                int g = (n0 + wn * 64) >> 6;     // wave's 64 cols = one sub-head
                int d = j * 16 + rl;             // 0..63
                int jp = j ^ 2;                  // paired fragment (d +/- 32)
                float sgn = (j < 2) ? -1.f : 1.f;
                for (int r = 0; r < 4; r++) {
                    int t = trow + r;
                    float c = costab[t * 32 + (d & 31)];
                    float s = sintab[t * 32 + (d & 31)];
                    float v = acc[i][j][r] * c + sgn * acc[i][jp][r] * s;
                    if (MODE == 1) v *= SCALING;
                    Cb[((size_t)g * 2048 + t) * 64 + d] = f2bf(v);
                }
            }
        }
    }
}

// ---------------- differential flash attention (barrier-free waves) ----------
// grid 512 blocks x 256 thr; wave (b,w) owns q-tile qt=63-(b>>3) (32 rows), g=(b&7)*4+w.
// Heavy tiles dispatch first (descending qt) for balance; b%8 pins g-quad to one XCD.
// K/V read directly from global (L2-resident); only P transposes through per-wave LDS.
__global__ __launch_bounds__(256)
void k_flash(const u16* __restrict__ qb, const u16* __restrict__ kb,
             const u16* __restrict__ vt, u16* __restrict__ Ob) {
    __shared__ u16 Pb[4][32][72];
    int b = blockIdx.x;
    int qt = 63 - (b >> 3);
    int tid = threadIdx.x, lane = tid & 63, wid = tid >> 6;
    int g = (b & 7) * 4 + wid;
    int h = g >> 1;
    int q0w = qt * 32;
    int rl = lane & 15, rg = lane >> 4;
    s16x8 aQ[2][2];
    for (int mf = 0; mf < 2; mf++)
        for (int ks = 0; ks < 2; ks++)
            aQ[mf][ks] = *(const s16x8*)(qb + ((size_t)(g * 2048 + q0w + mf * 16 + rl)) * 64 + ks * 32 + rg * 8);
    f32x4 Oa[2][8] = {};
    float mrow[2][4], lrow[2][4];
    for (int mf = 0; mf < 2; mf++)
        for (int r = 0; r < 4; r++) { mrow[mf][r] = -3e38f; lrow[mf][r] = 0.f; }
    int ntiles = (qt >> 1) + 1;
    for (int it = 0; it < ntiles; it++) {
        int kv0 = it * 64;
        bool maskt = (it == ntiles - 1);
        s16x8 bK[4][2];
        for (int nf = 0; nf < 4; nf++)
            for (int ks = 0; ks < 2; ks++)
                bK[nf][ks] = *(const s16x8*)(kb + ((size_t)(g * 2048 + kv0 + nf * 16 + rl)) * 64 + ks * 32 + rg * 8);
        f32x4 S[2][4];
        for (int mf = 0; mf < 2; mf++)
            for (int nf = 0; nf < 4; nf++) {
                f32x4 s = {};
                s = __builtin_amdgcn_mfma_f32_16x16x32_bf16(aQ[mf][0], bK[nf][0], s, 0, 0, 0);
                s = __builtin_amdgcn_mfma_f32_16x16x32_bf16(aQ[mf][1], bK[nf][1], s, 0, 0, 0);
                S[mf][nf] = s;
            }
        if (maskt) {
            for (int mf = 0; mf < 2; mf++)
                for (int nf = 0; nf < 4; nf++)
                    for (int r = 0; r < 4; r++) {
                        int kv = kv0 + nf * 16 + rl;
                        int q = q0w + mf * 16 + rg * 4 + r;
                        if (kv > q) S[mf][nf][r] = NEGV;
                    }
        }
        for (int mf = 0; mf < 2; mf++) {
            float nm[4];
            for (int r = 0; r < 4; r++) {
                float mx = S[mf][0][r];
                for (int nf = 1; nf < 4; nf++) mx = fmaxf(mx, S[mf][nf][r]);
                for (int msk = 1; msk < 16; msk <<= 1) mx = fmaxf(mx, __shfl_xor(mx, msk));
                nm[r] = fmaxf(mrow[mf][r], mx);
                float sc = __expf(mrow[mf][r] - nm[r]);
                mrow[mf][r] = nm[r];
                lrow[mf][r] *= sc;
                for (int nf = 0; nf < 8; nf++) Oa[mf][nf][r] *= sc;
            }
            for (int r = 0; r < 4; r++) {
                float rs = 0.f;
                for (int nf = 0; nf < 4; nf++) {
                    float p = __expf(S[mf][nf][r] - nm[r]);
                    S[mf][nf][r] = p;
                    rs += p;
                }
                for (int msk = 1; msk < 16; msk <<= 1) rs += __shfl_xor(rs, msk);
                lrow[mf][r] += rs;
            }
            for (int nf = 0; nf < 4; nf++)
                for (int r = 0; r < 4; r++)
                    Pb[wid][mf * 16 + rg * 4 + r][nf * 16 + rl] = f2bf(S[mf][nf][r]);
        }
        // per-wave LDS: no barrier needed (compiler inserts lgkmcnt waits)
        s16x8 aP[2][2];
        for (int mf = 0; mf < 2; mf++)
            for (int ks = 0; ks < 2; ks++)
                aP[mf][ks] = *(const s16x8*)&Pb[wid][mf * 16 + rl][ks * 32 + rg * 8];
        for (int ks = 0; ks < 2; ks++)
            for (int nf = 0; nf < 8; nf++) {
                s16x8 bV = *(const s16x8*)(vt + ((size_t)(h * 128 + nf * 16 + rl)) * 2048 + kv0 + ks * 32 + rg * 8);
                for (int mf = 0; mf < 2; mf++)
                    Oa[mf][nf] = __builtin_amdgcn_mfma_f32_16x16x32_bf16(aP[mf][ks], bV, Oa[mf][nf], 0, 0, 0);
            }
    }
    for (int mf = 0; mf < 2; mf++)
        for (int r = 0; r < 4; r++) {
            float inv = 1.f / lrow[mf][r];
            int t = q0w + mf * 16 + rg * 4 + r;
            for (int nf = 0; nf < 8; nf++)
                Ob[((size_t)(g * 2048 + t)) * 128 + nf * 16 + rl] = f2bf(Oa[mf][nf][r] * inv);
        }
}

// ---------------- combine O0 - lam*O1, RMSNorm, -> bf16 (t, e) ----------------
__global__ __launch_bounds__(256)
void k_combine(const u16* __restrict__ O, const float* __restrict__ lamp,
               const float* __restrict__ subw, u16* __restrict__ Ab) {
    int gw = blockIdx.x * 4 + (threadIdx.x >> 6);  // 0..32767
    int lane = threadIdx.x & 63;
    int h = gw >> 11;
    int t = gw & 2047;
    float lam = *lamp;
    const u16* o0 = O + ((size_t)((2 * h) * 2048 + t)) * 128 + lane * 2;
    const u16* o1 = O + ((size_t)((2 * h + 1) * 2048 + t)) * 128 + lane * 2;
    unsigned int p0 = *(const unsigned int*)o0;
    unsigned int p1 = *(const unsigned int*)o1;
    float a0 = bf2f(p0 & 0xffffu) - lam * bf2f(p1 & 0xffffu);
    float a1 = bf2f(p0 >> 16) - lam * bf2f(p1 >> 16);
    float ss = a0 * a0 + a1 * a1;
    for (int m = 1; m < 64; m <<= 1) ss += __shfl_xor(ss, m);
    float inv = rsqrtf(ss * (1.f / 128.f) + 1e-5f) * (1.f - LAMBDA_INIT);
    a0 *= inv * subw[lane * 2];
    a1 *= inv * subw[lane * 2 + 1];
    unsigned int pk = (unsigned int)f2bf(a0) | ((unsigned int)f2bf(a1) << 16);
    *(unsigned int*)(Ab + (size_t)t * 2048 + h * 128 + lane * 2) = pk;
}

extern "C" void kernel_launch(void* const* d_in, const int* in_sizes, int n_in,
                              void* d_out, int out_size, void* d_ws, size_t ws_size,
                              hipStream_t stream) {
    const float* x    = (const float*)d_in[0];
    const float* Wq   = (const float*)d_in[2];
    const float* Wk   = (const float*)d_in[3];
    const float* Wv   = (const float*)d_in[4];
    const float* Wo   = (const float*)d_in[5];
    const float* lq1  = (const float*)d_in[6];
    const float* lk1  = (const float*)d_in[7];
    const float* lq2  = (const float*)d_in[8];
    const float* lk2  = (const float*)d_in[9];
    const float* subw = (const float*)d_in[10];
    float* out = (float*)d_out;

    char* ws = (char*)d_ws;
    size_t off = 0;
    auto alloc = [&](size_t sz) -> char* {
        char* p = ws + off;
        off = (off + sz + 255) & ~(size_t)255;
        return p;
    };
    float* lam  = (float*)alloc(4);
    float* cost = (float*)alloc((size_t)T_SEQ * 32 * 4);
    float* sint = (float*)alloc((size_t)T_SEQ * 32 * 4);
    u16* xbf  = (u16*)alloc((size_t)T_SEQ * EMB * 2);
    u16* wqt  = (u16*)alloc((size_t)EMB * EMB * 2);
    u16* wkt  = (u16*)alloc((size_t)EMB * EMB * 2);
    u16* wvt  = (u16*)alloc((size_t)EMB * EMB * 2);
    u16* wot  = (u16*)alloc((size_t)EMB * EMB * 2);
    u16* qbf  = (u16*)alloc((size_t)G32 * T_SEQ * DH * 2);
    u16* kbf  = (u16*)alloc((size_t)G32 * T_SEQ * DH * 2);
    u16* vtb  = (u16*)alloc((size_t)NHEAD * DV * T_SEQ * 2);
    u16* Obuf = (u16*)alloc((size_t)G32 * T_SEQ * DV * 2);   // 16 MB
    u16* Abf  = (u16*)alloc((size_t)T_SEQ * EMB * 2);
    float* vraw = (float*)Obuf;  // alias: 16 MB, fully consumed before Obuf is written

    k_lambda<<<1, 64, 0, stream>>>(lq1, lk1, lq2, lk2, lam);
    k_ropetab<<<256, 256, 0, stream>>>(cost, sint);
    k_cvt_x<<<4096, 256, 0, stream>>>(x, xbf);
    dim3 tg(64, 64);
    k_transpose_cvt<<<tg, 256, 0, stream>>>(Wq, wqt);
    k_transpose_cvt<<<tg, 256, 0, stream>>>(Wk, wkt);
    k_transpose_cvt<<<tg, 256, 0, stream>>>(Wv, wvt);
    k_transpose_cvt<<<tg, 256, 0, stream>>>(Wo, wot);
    dim3 gg(16, 16);
    k_gemm<1><<<gg, 256, 0, stream>>>(xbf, wqt, nullptr, qbf, cost, sint);
    k_gemm<2><<<gg, 256, 0, stream>>>(xbf, wkt, nullptr, kbf, cost, sint);
    k_gemm<0><<<gg, 256, 0, stream>>>(xbf, wvt, vraw, nullptr, nullptr, nullptr);
    k_transpose_cvt<<<tg, 256, 0, stream>>>(vraw, vtb);
    k_flash<<<512, 256, 0, stream>>>(qbf, kbf, vtb, Obuf);
    k_combine<<<8192, 256, 0, stream>>>(Obuf, lam, subw, Abf);
    k_gemm<0><<<gg, 256, 0, stream>>>(Abf, wot, out, nullptr, nullptr, nullptr);
}

// Round 3
// 258.725 us; speedup vs baseline: 1.5416x; 1.5416x over previous
//
#include <hip/hip_runtime.h>

typedef __attribute__((ext_vector_type(4))) float f32x4;
typedef __attribute__((ext_vector_type(8))) short s16x8;
typedef __attribute__((ext_vector_type(4))) short s16x4;
typedef unsigned short u16;

#define T_SEQ 2048
#define EMB   2048
#define NHEAD 16
#define G32   32
#define DH    64
#define DV    128
#define NEGV  (-1e9f)
// LAMBDA_INIT = 0.8 - 0.6*exp(-0.3*12)
#define LAMBDA_INIT 0.7836057665316245f
#define SCALING 0.125f

__device__ __forceinline__ u16 f2bf(float f) {
    unsigned int u = __builtin_bit_cast(unsigned int, f);
    unsigned int r = (u + 0x7fffu + ((u >> 16) & 1u)) >> 16;
    return (u16)r;
}
__device__ __forceinline__ float bf2f(unsigned int u) {
    return __builtin_bit_cast(float, u << 16);
}

// ---------------- lambda scalar ----------------
__global__ void k_lambda(const float* lq1, const float* lk1,
                         const float* lq2, const float* lk2, float* lam) {
    int l = threadIdx.x;  // 64
    float a = lq1[l] * lk1[l];
    float b = lq2[l] * lk2[l];
    for (int m = 32; m; m >>= 1) { a += __shfl_xor(a, m); b += __shfl_xor(b, m); }
    if (l == 0) *lam = __expf(a) - __expf(b) + LAMBDA_INIT;
}

// ---------------- rope tables (2048 x 32) ----------------
__global__ void k_ropetab(float* cost, float* sint) {
    int i = blockIdx.x * 256 + threadIdx.x;  // 65536
    int j = i & 31, t = i >> 5;
    double invf = exp(-(double)j * (9.210340371976184 / 32.0));  // 10000^(-j/32)
    double fr = (double)t * invf;
    cost[i] = (float)cos(fr);
    sint[i] = (float)sin(fr);
}

// ---------------- x fp32 -> bf16 ----------------
__global__ void k_cvt_x(const float* __restrict__ in, u16* __restrict__ out) {
    int i = blockIdx.x * 256 + threadIdx.x;  // one per 4 elems
    f32x4 v = *(const f32x4*)(in + (size_t)i * 4);
    s16x4 o;
    for (int j = 0; j < 4; j++) o[j] = (short)f2bf(v[j]);
    *(s16x4*)(out + (size_t)i * 4) = o;
}

// ---------------- 2048x2048 fp32 -> transposed bf16 ----------------
__global__ __launch_bounds__(256)
void k_transpose_cvt(const float* __restrict__ in, u16* __restrict__ out) {
    __shared__ float tile[32][33];
    int lc = threadIdx.x & 31;
    int lr0 = (threadIdx.x >> 5) * 4;
    int col = blockIdx.x * 32 + lc;
    int row0 = blockIdx.y * 32 + lr0;
    for (int r = 0; r < 4; r++)
        tile[lr0 + r][lc] = in[(size_t)(row0 + r) * 2048 + col];
    __syncthreads();
    int ncol = blockIdx.y * 32 + lc;
    int nrow0 = blockIdx.x * 32 + lr0;
    for (int r = 0; r < 4; r++)
        out[(size_t)(nrow0 + r) * 2048 + ncol] = f2bf(tile[lc][lr0 + r]);
}

// ---------------- GEMM: C = A(bf16,row-major MxK) @ Bt(bf16, NxK)^T ----------
// MODE 0: split-K=2 (gridDim.z) -> fp32 partials Cf[z*4M + ...]
// MODE 1: fused QK (N=4096): rope epilogue -> qbf (cols<2048, *SCALING) / kbf
template <int MODE>
__global__ __launch_bounds__(256)
void k_gemm(const u16* __restrict__ A, const u16* __restrict__ Bt,
            float* __restrict__ Cf, u16* __restrict__ Cb,
            const float* __restrict__ costab, const float* __restrict__ sintab) {
    __shared__ u16 As[128][40];
    __shared__ u16 Bs[128][40];
    int t0 = blockIdx.y * 128, n0 = blockIdx.x * 128;
    int k_lo = 0, k_hi = 2048;
    if (MODE == 0) {
        k_lo = blockIdx.z * 1024; k_hi = k_lo + 1024;
        Cf += (size_t)blockIdx.z * 2048 * 2048;
    }
    int tid = threadIdx.x;
    int lane = tid & 63, wid = tid >> 6;
    int wm = wid >> 1, wn = wid & 1;
    int rl = lane & 15, rg = lane >> 4;
    int srow = tid >> 2;          // 0..63
    int scol = (tid & 3) * 8;     // 0,8,16,24
    f32x4 acc[4][4] = {};
    for (int k0 = k_lo; k0 < k_hi; k0 += 32) {
        __syncthreads();
        const u16* pa = A + (size_t)(t0 + srow) * 2048 + k0 + scol;
        s16x8 va0 = *(const s16x8*)pa;
        s16x8 va1 = *(const s16x8*)(pa + (size_t)64 * 2048);
        const u16* pb = Bt + (size_t)(n0 + srow) * 2048 + k0 + scol;
        s16x8 vb0 = *(const s16x8*)pb;
        s16x8 vb1 = *(const s16x8*)(pb + (size_t)64 * 2048);
        *(s16x8*)&As[srow][scol] = va0;
        *(s16x8*)&As[srow + 64][scol] = va1;
        *(s16x8*)&Bs[srow][scol] = vb0;
        *(s16x8*)&Bs[srow + 64][scol] = vb1;
        __syncthreads();
        s16x8 af[4], bfr[4];
        for (int i = 0; i < 4; i++) af[i]  = *(const s16x8*)&As[wm * 64 + i * 16 + rl][rg * 8];
        for (int j = 0; j < 4; j++) bfr[j] = *(const s16x8*)&Bs[wn * 64 + j * 16 + rl][rg * 8];
        for (int i = 0; i < 4; i++)
            for (int j = 0; j < 4; j++)
                acc[i][j] = __builtin_amdgcn_mfma_f32_16x16x32_bf16(af[i], bfr[j], acc[i][j], 0, 0, 0);
    }
    // epilogue
    if (MODE == 0) {
        for (int i = 0; i < 4; i++) {
            int trow = t0 + wm * 64 + i * 16 + rg * 4;
            for (int j = 0; j < 4; j++) {
                int col = n0 + wn * 64 + j * 16 + rl;
                for (int r = 0; r < 4; r++)
                    Cf[(size_t)(trow + r) * 2048 + col] = acc[i][j][r];
            }
        }
    } else {
        int nbase = n0 + wn * 64;              // wave's 64 cols = one sub-head
        const bool isQ = nbase < 2048;
        u16* dst = isQ ? Cb : Cb + (size_t)G32 * 2048 * 64;
        int g = (isQ ? nbase : nbase - 2048) >> 6;
        float fs = isQ ? SCALING : 1.0f;
        for (int i = 0; i < 4; i++) {
            int trow = t0 + wm * 64 + i * 16 + rg * 4;
            for (int j = 0; j < 4; j++) {
                int d = j * 16 + rl;             // 0..63
                int jp = j ^ 2;                  // paired fragment (d +/- 32)
                float sgn = (j < 2) ? -1.f : 1.f;
                for (int r = 0; r < 4; r++) {
                    int t = trow + r;
                    float c = costab[t * 32 + (d & 31)];
                    float s = sintab[t * 32 + (d & 31)];
                    float v = (acc[i][j][r] * c + sgn * acc[i][jp][r] * s) * fs;
                    dst[((size_t)g * 2048 + t) * 64 + d] = f2bf(v);
                }
            }
        }
    }
}

// ---------------- partial adds ----------------
__global__ void k_vadd(const float* __restrict__ p, u16* __restrict__ vtb) {
    int i = blockIdx.x * 256 + threadIdx.x;  // per 4 elems
    f32x4 a = *(const f32x4*)(p + (size_t)i * 4);
    f32x4 b = *(const f32x4*)(p + (size_t)4194304 + i * 4);
    s16x4 o;
    for (int j = 0; j < 4; j++) o[j] = (short)f2bf(a[j] + b[j]);
    *(s16x4*)(vtb + (size_t)i * 4) = o;
}
__global__ void k_oadd(const float* __restrict__ p, float* __restrict__ out) {
    int i = blockIdx.x * 256 + threadIdx.x;
    f32x4 a = *(const f32x4*)(p + (size_t)i * 4);
    f32x4 b = *(const f32x4*)(p + (size_t)4194304 + i * 4);
    for (int j = 0; j < 4; j++) a[j] += b[j];
    *(f32x4*)(out + (size_t)i * 4) = a;
}

// ---------------- differential flash attention ----------------
// grid 1024 = (32 qb x 32 g), heavy qb first; 256 thr = 4 waves x 16 q-rows.
// Block q-tile = 64 rows (qb). K/V staged in padded LDS; P via per-wave LDS.
__global__ __launch_bounds__(256, 4)
void k_flash(const u16* __restrict__ qb_, const u16* __restrict__ kb,
             const u16* __restrict__ vt, u16* __restrict__ Ob) {
    __shared__ u16 Kt[64][72];
    __shared__ u16 Vt[128][72];
    __shared__ u16 Pb[4][16][72];
    int b = blockIdx.x;
    int qt = 31 - (b >> 5);       // heavy tiles dispatch first
    int g = b & 31;
    int h = g >> 1;
    int tid = threadIdx.x, lane = tid & 63, wid = tid >> 6;
    int q0w = qt * 64 + wid * 16;
    int rl = lane & 15, rg = lane >> 4;
    s16x8 aQ[2];
    for (int ks = 0; ks < 2; ks++)
        aQ[ks] = *(const s16x8*)(qb_ + ((size_t)(g * 2048 + q0w + rl)) * 64 + ks * 32 + rg * 8);
    f32x4 Oa[8] = {};
    float mrow[4], lrow[4];
    for (int r = 0; r < 4; r++) { mrow[r] = -3e38f; lrow[r] = 0.f; }
    int ntiles = qt + 1;
    int srow = tid >> 3;          // 0..31
    int scol = (tid & 7) * 8;     // 0..56
    for (int it = 0; it < ntiles; it++) {
        int kv0 = it * 64;
        bool maskt = (it == ntiles - 1);
        __syncthreads();
        {
            s16x8 vk[2], vv[4];
            for (int p = 0; p < 2; p++)
                vk[p] = *(const s16x8*)(kb + ((size_t)(g * 2048 + kv0 + srow + p * 32)) * 64 + scol);
            for (int p = 0; p < 4; p++)
                vv[p] = *(const s16x8*)(vt + ((size_t)(h * 128 + srow + p * 32)) * 2048 + kv0 + scol);
            for (int p = 0; p < 2; p++) *(s16x8*)&Kt[srow + p * 32][scol] = vk[p];
            for (int p = 0; p < 4; p++) *(s16x8*)&Vt[srow + p * 32][scol] = vv[p];
        }
        __syncthreads();
        s16x8 bK[4][2];
        for (int nf = 0; nf < 4; nf++)
            for (int ks = 0; ks < 2; ks++)
                bK[nf][ks] = *(const s16x8*)&Kt[nf * 16 + rl][ks * 32 + rg * 8];
        f32x4 S[4];
        for (int nf = 0; nf < 4; nf++) {
            f32x4 s = {};
            s = __builtin_amdgcn_mfma_f32_16x16x32_bf16(aQ[0], bK[nf][0], s, 0, 0, 0);
            s = __builtin_amdgcn_mfma_f32_16x16x32_bf16(aQ[1], bK[nf][1], s, 0, 0, 0);
            S[nf] = s;
        }
        if (maskt) {
            for (int nf = 0; nf < 4; nf++)
                for (int r = 0; r < 4; r++) {
                    int kv = kv0 + nf * 16 + rl;
                    int q = q0w + rg * 4 + r;
                    if (kv > q) S[nf][r] = NEGV;
                }
        }
        float nm[4];
        for (int r = 0; r < 4; r++) {
            float mx = S[0][r];
            for (int nf = 1; nf < 4; nf++) mx = fmaxf(mx, S[nf][r]);
            for (int msk = 1; msk < 16; msk <<= 1) mx = fmaxf(mx, __shfl_xor(mx, msk));
            nm[r] = fmaxf(mrow[r], mx);
            float sc = __expf(mrow[r] - nm[r]);
            mrow[r] = nm[r];
            lrow[r] *= sc;
            for (int nf = 0; nf < 8; nf++) Oa[nf][r] *= sc;
        }
        for (int r = 0; r < 4; r++) {
            float rs = 0.f;
            for (int nf = 0; nf < 4; nf++) {
                float p = __expf(S[nf][r] - nm[r]);
                S[nf][r] = p;
                rs += p;
            }
            for (int msk = 1; msk < 16; msk <<= 1) rs += __shfl_xor(rs, msk);
            lrow[r] += rs;
        }
        for (int nf = 0; nf < 4; nf++)
            for (int r = 0; r < 4; r++)
                Pb[wid][rg * 4 + r][nf * 16 + rl] = f2bf(S[nf][r]);
        // per-wave LDS round-trip: no barrier needed
        s16x8 aP[2];
        for (int ks = 0; ks < 2; ks++)
            aP[ks] = *(const s16x8*)&Pb[wid][rl][ks * 32 + rg * 8];
        for (int ks = 0; ks < 2; ks++)
            for (int nf = 0; nf < 8; nf++) {
                s16x8 bV = *(const s16x8*)&Vt[nf * 16 + rl][ks * 32 + rg * 8];
                Oa[nf] = __builtin_amdgcn_mfma_f32_16x16x32_bf16(aP[ks], bV, Oa[nf], 0, 0, 0);
            }
    }
    for (int r = 0; r < 4; r++) {
        float inv = 1.f / lrow[r];
        int t = q0w + rg * 4 + r;
        for (int nf = 0; nf < 8; nf++)
            Ob[((size_t)(g * 2048 + t)) * 128 + nf * 16 + rl] = f2bf(Oa[nf][r] * inv);
    }
}

// ---------------- combine O0 - lam*O1, RMSNorm, -> bf16 (t, e) ----------------
__global__ __launch_bounds__(256)
void k_combine(const u16* __restrict__ O, const float* __restrict__ lamp,
               const float* __restrict__ subw, u16* __restrict__ Ab) {
    int gw = blockIdx.x * 4 + (threadIdx.x >> 6);  // 0..32767
    int lane = threadIdx.x & 63;
    int h = gw >> 11;
    int t = gw & 2047;
    float lam = *lamp;
    const u16* o0 = O + ((size_t)((2 * h) * 2048 + t)) * 128 + lane * 2;
    const u16* o1 = O + ((size_t)((2 * h + 1) * 2048 + t)) * 128 + lane * 2;
    unsigned int p0 = *(const unsigned int*)o0;
    unsigned int p1 = *(const unsigned int*)o1;
    float a0 = bf2f(p0 & 0xffffu) - lam * bf2f(p1 & 0xffffu);
    float a1 = bf2f(p0 >> 16) - lam * bf2f(p1 >> 16);
    float ss = a0 * a0 + a1 * a1;
    for (int m = 1; m < 64; m <<= 1) ss += __shfl_xor(ss, m);
    float inv = rsqrtf(ss * (1.f / 128.f) + 1e-5f) * (1.f - LAMBDA_INIT);
    a0 *= inv * subw[lane * 2];
    a1 *= inv * subw[lane * 2 + 1];
    unsigned int pk = (unsigned int)f2bf(a0) | ((unsigned int)f2bf(a1) << 16);
    *(unsigned int*)(Ab + (size_t)t * 2048 + h * 128 + lane * 2) = pk;
}

extern "C" void kernel_launch(void* const* d_in, const int* in_sizes, int n_in,
                              void* d_out, int out_size, void* d_ws, size_t ws_size,
                              hipStream_t stream) {
    const float* x    = (const float*)d_in[0];
    const float* Wq   = (const float*)d_in[2];
    const float* Wk   = (const float*)d_in[3];
    const float* Wv   = (const float*)d_in[4];
    const float* Wo   = (const float*)d_in[5];
    const float* lq1  = (const float*)d_in[6];
    const float* lk1  = (const float*)d_in[7];
    const float* lq2  = (const float*)d_in[8];
    const float* lk2  = (const float*)d_in[9];
    const float* subw = (const float*)d_in[10];
    float* out = (float*)d_out;

    char* ws = (char*)d_ws;
    size_t off = 0;
    auto alloc = [&](size_t sz) -> char* {
        char* p = ws + off;
        off = (off + sz + 255) & ~(size_t)255;
        return p;
    };
    float* lam  = (float*)alloc(4);
    float* cost = (float*)alloc((size_t)T_SEQ * 32 * 4);
    float* sint = (float*)alloc((size_t)T_SEQ * 32 * 4);
    u16* xbf   = (u16*)alloc((size_t)T_SEQ * EMB * 2);
    u16* wqkt  = (u16*)alloc((size_t)2 * EMB * EMB * 2);   // wqt | wkt contiguous
    u16* wvt   = (u16*)alloc((size_t)EMB * EMB * 2);
    u16* wot   = (u16*)alloc((size_t)EMB * EMB * 2);
    u16* qkbuf = (u16*)alloc((size_t)2 * G32 * T_SEQ * DH * 2);  // qbf | kbf
    u16* vtb   = (u16*)alloc((size_t)NHEAD * DV * T_SEQ * 2);
    u16* Obuf  = (u16*)alloc((size_t)G32 * T_SEQ * DV * 2);
    u16* Abf   = (u16*)alloc((size_t)T_SEQ * EMB * 2);
    float* parts = (float*)alloc((size_t)2 * EMB * EMB * 4);     // split-K partials
    u16* wqt = wqkt;
    u16* wkt = wqkt + (size_t)EMB * EMB;
    u16* qbf = qkbuf;
    u16* kbf = qkbuf + (size_t)G32 * T_SEQ * DH;

    k_lambda<<<1, 64, 0, stream>>>(lq1, lk1, lq2, lk2, lam);
    k_ropetab<<<256, 256, 0, stream>>>(cost, sint);
    k_cvt_x<<<4096, 256, 0, stream>>>(x, xbf);
    dim3 tg(64, 64);
    k_transpose_cvt<<<tg, 256, 0, stream>>>(Wq, wqt);
    k_transpose_cvt<<<tg, 256, 0, stream>>>(Wk, wkt);
    k_transpose_cvt<<<tg, 256, 0, stream>>>(Wv, wvt);
    k_transpose_cvt<<<tg, 256, 0, stream>>>(Wo, wot);
    // fused Q|K projection (N=4096), rope epilogue
    k_gemm<1><<<dim3(32, 16), 256, 0, stream>>>(xbf, wqkt, nullptr, qkbuf, cost, sint);
    // V^T = wvt @ xbf^T, split-K=2
    k_gemm<0><<<dim3(16, 16, 2), 256, 0, stream>>>(wvt, xbf, parts, nullptr, nullptr, nullptr);
    k_vadd<<<4096, 256, 0, stream>>>(parts, vtb);
    k_flash<<<1024, 256, 0, stream>>>(qbf, kbf, vtb, Obuf);
    k_combine<<<8192, 256, 0, stream>>>(Obuf, lam, subw, Abf);
    // out projection, split-K=2
    k_gemm<0><<<dim3(16, 16, 2), 256, 0, stream>>>(Abf, wot, parts, nullptr, nullptr, nullptr);
    k_oadd<<<4096, 256, 0, stream>>>(parts, out);
}

// Round 4
// 255.547 us; speedup vs baseline: 1.5608x; 1.0124x over previous
//
#include <hip/hip_runtime.h>

typedef __attribute__((ext_vector_type(4))) float f32x4;
typedef __attribute__((ext_vector_type(8))) short s16x8;
typedef __attribute__((ext_vector_type(4))) short s16x4;
typedef __attribute__((ext_vector_type(2))) unsigned int u32x2;
typedef unsigned short u16;

#define T_SEQ 2048
#define EMB   2048
#define NHEAD 16
#define G32   32
#define DH    64
#define DV    128
#define NEGV  (-1e9f)
// LAMBDA_INIT = 0.8 - 0.6*exp(-0.3*12)
#define LAMBDA_INIT 0.7836057665316245f
#define SCALING 0.125f

__device__ __forceinline__ u16 f2bf(float f) {
    unsigned int u = __builtin_bit_cast(unsigned int, f);
    unsigned int r = (u + 0x7fffu + ((u >> 16) & 1u)) >> 16;
    return (u16)r;
}
__device__ __forceinline__ float bf2f(unsigned int u) {
    return __builtin_bit_cast(float, u << 16);
}
__device__ __forceinline__ unsigned int cvt_pk_bf16(float lo, float hi) {
    unsigned int r;
    asm("v_cvt_pk_bf16_f32 %0, %1, %2" : "=v"(r) : "v"(lo), "v"(hi));
    return r;
}

// ---------------- lambda scalar ----------------
__global__ void k_lambda(const float* lq1, const float* lk1,
                         const float* lq2, const float* lk2, float* lam) {
    int l = threadIdx.x;  // 64
    float a = lq1[l] * lk1[l];
    float b = lq2[l] * lk2[l];
    for (int m = 32; m; m >>= 1) { a += __shfl_xor(a, m); b += __shfl_xor(b, m); }
    if (l == 0) *lam = __expf(a) - __expf(b) + LAMBDA_INIT;
}

// ---------------- rope tables (2048 x 32) ----------------
__global__ void k_ropetab(float* cost, float* sint) {
    int i = blockIdx.x * 256 + threadIdx.x;  // 65536
    int j = i & 31, t = i >> 5;
    double invf = exp(-(double)j * (9.210340371976184 / 32.0));  // 10000^(-j/32)
    double fr = (double)t * invf;
    cost[i] = (float)cos(fr);
    sint[i] = (float)sin(fr);
}

// ---------------- x fp32 -> bf16 ----------------
__global__ void k_cvt_x(const float* __restrict__ in, u16* __restrict__ out) {
    int i = blockIdx.x * 256 + threadIdx.x;  // one per 4 elems
    f32x4 v = *(const f32x4*)(in + (size_t)i * 4);
    s16x4 o;
    for (int j = 0; j < 4; j++) o[j] = (short)f2bf(v[j]);
    *(s16x4*)(out + (size_t)i * 4) = o;
}

// ---------------- 2048x2048 fp32 -> transposed bf16 ----------------
__global__ __launch_bounds__(256)
void k_transpose_cvt(const float* __restrict__ in, u16* __restrict__ out) {
    __shared__ float tile[32][33];
    int lc = threadIdx.x & 31;
    int lr0 = (threadIdx.x >> 5) * 4;
    int col = blockIdx.x * 32 + lc;
    int row0 = blockIdx.y * 32 + lr0;
    for (int r = 0; r < 4; r++)
        tile[lr0 + r][lc] = in[(size_t)(row0 + r) * 2048 + col];
    __syncthreads();
    int ncol = blockIdx.y * 32 + lc;
    int nrow0 = blockIdx.x * 32 + lr0;
    for (int r = 0; r < 4; r++)
        out[(size_t)(nrow0 + r) * 2048 + ncol] = f2bf(tile[lc][lr0 + r]);
}

// ---------------- GEMM: C = A(bf16,row-major MxK) @ Bt(bf16, NxK)^T ----------
// MODE 0: split-K=2 (gridDim.z) -> fp32 partials Cf[z*4M + ...]
// MODE 1: fused QK (N=4096): rope epilogue -> qbf (cols<2048, *SCALING) / kbf
template <int MODE>
__global__ __launch_bounds__(256)
void k_gemm(const u16* __restrict__ A, const u16* __restrict__ Bt,
            float* __restrict__ Cf, u16* __restrict__ Cb,
            const float* __restrict__ costab, const float* __restrict__ sintab) {
    __shared__ u16 As[128][40];
    __shared__ u16 Bs[128][40];
    int t0 = blockIdx.y * 128, n0 = blockIdx.x * 128;
    int k_lo = 0, k_hi = 2048;
    if (MODE == 0) {
        k_lo = blockIdx.z * 1024; k_hi = k_lo + 1024;
        Cf += (size_t)blockIdx.z * 2048 * 2048;
    }
    int tid = threadIdx.x;
    int lane = tid & 63, wid = tid >> 6;
    int wm = wid >> 1, wn = wid & 1;
    int rl = lane & 15, rg = lane >> 4;
    int srow = tid >> 2;          // 0..63
    int scol = (tid & 3) * 8;     // 0,8,16,24
    f32x4 acc[4][4] = {};
    for (int k0 = k_lo; k0 < k_hi; k0 += 32) {
        __syncthreads();
        const u16* pa = A + (size_t)(t0 + srow) * 2048 + k0 + scol;
        s16x8 va0 = *(const s16x8*)pa;
        s16x8 va1 = *(const s16x8*)(pa + (size_t)64 * 2048);
        const u16* pb = Bt + (size_t)(n0 + srow) * 2048 + k0 + scol;
        s16x8 vb0 = *(const s16x8*)pb;
        s16x8 vb1 = *(const s16x8*)(pb + (size_t)64 * 2048);
        *(s16x8*)&As[srow][scol] = va0;
        *(s16x8*)&As[srow + 64][scol] = va1;
        *(s16x8*)&Bs[srow][scol] = vb0;
        *(s16x8*)&Bs[srow + 64][scol] = vb1;
        __syncthreads();
        s16x8 af[4], bfr[4];
        for (int i = 0; i < 4; i++) af[i]  = *(const s16x8*)&As[wm * 64 + i * 16 + rl][rg * 8];
        for (int j = 0; j < 4; j++) bfr[j] = *(const s16x8*)&Bs[wn * 64 + j * 16 + rl][rg * 8];
        for (int i = 0; i < 4; i++)
            for (int j = 0; j < 4; j++)
                acc[i][j] = __builtin_amdgcn_mfma_f32_16x16x32_bf16(af[i], bfr[j], acc[i][j], 0, 0, 0);
    }
    // epilogue
    if (MODE == 0) {
        for (int i = 0; i < 4; i++) {
            int trow = t0 + wm * 64 + i * 16 + rg * 4;
            for (int j = 0; j < 4; j++) {
                int col = n0 + wn * 64 + j * 16 + rl;
                for (int r = 0; r < 4; r++)
                    Cf[(size_t)(trow + r) * 2048 + col] = acc[i][j][r];
            }
        }
    } else {
        int nbase = n0 + wn * 64;              // wave's 64 cols = one sub-head
        const bool isQ = nbase < 2048;
        u16* dst = isQ ? Cb : Cb + (size_t)G32 * 2048 * 64;
        int g = (isQ ? nbase : nbase - 2048) >> 6;
        float fs = isQ ? SCALING : 1.0f;
        for (int i = 0; i < 4; i++) {
            int trow = t0 + wm * 64 + i * 16 + rg * 4;
            for (int j = 0; j < 4; j++) {
                int d = j * 16 + rl;             // 0..63
                int jp = j ^ 2;                  // paired fragment (d +/- 32)
                float sgn = (j < 2) ? -1.f : 1.f;
                for (int r = 0; r < 4; r++) {
                    int t = trow + r;
                    float c = costab[t * 32 + (d & 31)];
                    float s = sintab[t * 32 + (d & 31)];
                    float v = (acc[i][j][r] * c + sgn * acc[i][jp][r] * s) * fs;
                    dst[((size_t)g * 2048 + t) * 64 + d] = f2bf(v);
                }
            }
        }
    }
}

// ---------------- partial adds ----------------
__global__ void k_vadd(const float* __restrict__ p, u16* __restrict__ vtb) {
    int i = blockIdx.x * 256 + threadIdx.x;  // per 4 elems
    f32x4 a = *(const f32x4*)(p + (size_t)i * 4);
    f32x4 b = *(const f32x4*)(p + (size_t)4194304 + i * 4);
    s16x4 o;
    for (int j = 0; j < 4; j++) o[j] = (short)f2bf(a[j] + b[j]);
    *(s16x4*)(vtb + (size_t)i * 4) = o;
}
__global__ void k_oadd(const float* __restrict__ p, float* __restrict__ out) {
    int i = blockIdx.x * 256 + threadIdx.x;
    f32x4 a = *(const f32x4*)(p + (size_t)i * 4);
    f32x4 b = *(const f32x4*)(p + (size_t)4194304 + i * 4);
    for (int j = 0; j < 4; j++) a[j] += b[j];
    *(f32x4*)(out + (size_t)i * 4) = a;
}

// ---------------- differential flash attention (swapped-QK, in-reg softmax) --
// grid 1024 = (32 qb x 32 g), heavy qb first; 256 thr = 4 waves x 16 q-rows.
// K: direct global->frag regs (L2), prefetched 1 tile ahead.
// V: double-buffered XOR-swizzled LDS, 1 barrier/tile.
// S^T = mfma(K,Q): lane rl holds full row q=q0w+rl -> in-reg max/sum trees.
// P: cvt_pk -> per-wave swizzled LDS (ds_write_b64 x4, ds_read_b128 x2).
__global__ __launch_bounds__(256, 3)
void k_flash(const u16* __restrict__ qb_, const u16* __restrict__ kb,
             const u16* __restrict__ vt, u16* __restrict__ Ob) {
    __shared__ u16 Vt[2][128 * 64];
    __shared__ u16 Pb[4][16 * 64];
    int b = blockIdx.x;
    int qt = 31 - (b >> 5);       // heavy tiles dispatch first
    int g = b & 31;               // same-g blocks share XCD (b%8 preserved mod 32)
    int h = g >> 1;
    int tid = threadIdx.x, lane = tid & 63, wid = tid >> 6;
    int q0w = qt * 64 + wid * 16;
    int rl = lane & 15, rg = lane >> 4;
    int rl7s = (rl & 7) << 4;     // bank swizzle
    // Q fragments (operand B of swapped QK)
    s16x8 aQ[2];
    const u16* qbase = qb_ + ((size_t)(g * 2048 + q0w + rl)) * 64 + rg * 8;
    aQ[0] = *(const s16x8*)qbase;
    aQ[1] = *(const s16x8*)(qbase + 32);
    // staging / fragment address bases
    int srow = tid >> 3;          // 0..31
    int scol = (tid & 7) * 8;     // 0..56
    const u16* vbase = vt + ((size_t)(h * 128 + srow)) * 2048 + scol;
    const u16* kbase = kb + ((size_t)(g * 2048 + rl)) * 64 + rg * 8;
    // prologue: tile 0 into regs
    s16x8 vv[4], bK[4][2];
    for (int p = 0; p < 4; p++) vv[p] = *(const s16x8*)(vbase + (size_t)p * 32 * 2048);
    for (int nf = 0; nf < 4; nf++)
        for (int ks = 0; ks < 2; ks++)
            bK[nf][ks] = *(const s16x8*)(kbase + (size_t)nf * 16 * 64 + ks * 32);
    f32x4 Oa[8] = {};
    float mrow = -3e38f, lrow = 0.f;
    char* pbw = (char*)&Pb[wid][0] + rl * 128;
    int ntiles = qt + 1;
    for (int it = 0; it < ntiles; it++) {
        int kv0 = it * 64;
        char* Vb = (char*)&Vt[it & 1][0];
        // write staged V (swizzled)
        for (int p = 0; p < 4; p++) {
            int row = srow + p * 32;
            *(s16x8*)(Vb + ((row * 128 + scol * 2) ^ ((row & 7) << 4))) = vv[p];
        }
        bool more = (it + 1 < ntiles);
        if (more)
            for (int p = 0; p < 4; p++)
                vv[p] = *(const s16x8*)(vbase + (size_t)p * 32 * 2048 + kv0 + 64);
        __syncthreads();
        // S^T = K.Q^T : St[nf][r] = S[kv0+nf*16+rg*4+r][q0w+rl]
        f32x4 St[4];
        for (int nf = 0; nf < 4; nf++) {
            f32x4 s = {};
            s = __builtin_amdgcn_mfma_f32_16x16x32_bf16(bK[nf][0], aQ[0], s, 0, 0, 0);
            s = __builtin_amdgcn_mfma_f32_16x16x32_bf16(bK[nf][1], aQ[1], s, 0, 0, 0);
            St[nf] = s;
        }
        if (more)
            for (int nf = 0; nf < 4; nf++)
                for (int ks = 0; ks < 2; ks++)
                    bK[nf][ks] = *(const s16x8*)(kbase + (size_t)(kv0 + 64 + nf * 16) * 64 + ks * 32);
        if (it == ntiles - 1) {
            int q = q0w + rl;
            for (int nf = 0; nf < 4; nf++)
                for (int r = 0; r < 4; r++)
                    if (kv0 + nf * 16 + rg * 4 + r > q) St[nf][r] = NEGV;
        }
        // row max: in-reg tree + 2 cross-lane steps (all 16 regs share q=rl)
        float m0 = fmaxf(fmaxf(St[0][0], St[0][1]), fmaxf(St[0][2], St[0][3]));
        float m1 = fmaxf(fmaxf(St[1][0], St[1][1]), fmaxf(St[1][2], St[1][3]));
        float m2 = fmaxf(fmaxf(St[2][0], St[2][1]), fmaxf(St[2][2], St[2][3]));
        float m3 = fmaxf(fmaxf(St[3][0], St[3][1]), fmaxf(St[3][2], St[3][3]));
        float pmax = fmaxf(fmaxf(m0, m1), fmaxf(m2, m3));
        pmax = fmaxf(pmax, __shfl_xor(pmax, 16));
        pmax = fmaxf(pmax, __shfl_xor(pmax, 32));
        // defer-max (T13): only rescale when max grew past threshold
        if (__any(pmax > mrow + 8.f)) {
            float nm = fmaxf(mrow, pmax);
            float sc = __expf(mrow - nm);
            mrow = nm;
            lrow *= sc;
            int sci = __builtin_bit_cast(int, sc);
            for (int r = 0; r < 4; r++) {
                float sr = __builtin_bit_cast(float,
                    __builtin_amdgcn_ds_bpermute((rg * 20 + r) * 4, sci));
                for (int nf = 0; nf < 8; nf++) Oa[nf][r] *= sr;
            }
        }
        // P = exp(S - mrow)  (bounded by e^8)
        for (int nf = 0; nf < 4; nf++)
            for (int r = 0; r < 4; r++)
                St[nf][r] = __expf(St[nf][r] - mrow);
        float s0 = (St[0][0] + St[0][1]) + (St[0][2] + St[0][3]);
        float s1 = (St[1][0] + St[1][1]) + (St[1][2] + St[1][3]);
        float s2 = (St[2][0] + St[2][1]) + (St[2][2] + St[2][3]);
        float s3 = (St[3][0] + St[3][1]) + (St[3][2] + St[3][3]);
        float rs = (s0 + s1) + (s2 + s3);
        rs += __shfl_xor(rs, 16);
        rs += __shfl_xor(rs, 32);
        lrow += rs;
        // pack P^T -> row-q LDS (per-wave, swizzled), then read A-fragments
        for (int nf = 0; nf < 4; nf++) {
            unsigned int w0 = cvt_pk_bf16(St[nf][0], St[nf][1]);
            unsigned int w1 = cvt_pk_bf16(St[nf][2], St[nf][3]);
            u32x2 wp = {w0, w1};
            *(u32x2*)(pbw + ((nf * 32 + rg * 8) ^ rl7s)) = wp;
        }
        s16x8 aP[2];
        for (int ks = 0; ks < 2; ks++)
            aP[ks] = *(const s16x8*)(pbw + ((ks * 64 + rg * 16) ^ rl7s));
        // PV
        for (int ks = 0; ks < 2; ks++)
            for (int nf = 0; nf < 8; nf++) {
                int row = nf * 16 + rl;
                s16x8 bV = *(const s16x8*)(Vb + ((row * 128 + ks * 64 + rg * 16) ^ rl7s));
                Oa[nf] = __builtin_amdgcn_mfma_f32_16x16x32_bf16(aP[ks], bV, Oa[nf], 0, 0, 0);
            }
    }
    // epilogue: broadcast 1/l to Oa rows, write bf16
    float inv = 1.f / lrow;
    int invi = __builtin_bit_cast(int, inv);
    for (int r = 0; r < 4; r++) {
        float ir = __builtin_bit_cast(float,
            __builtin_amdgcn_ds_bpermute((rg * 20 + r) * 4, invi));
        int t = q0w + rg * 4 + r;
        for (int nf = 0; nf < 8; nf++)
            Ob[((size_t)(g * 2048 + t)) * 128 + nf * 16 + rl] = f2bf(Oa[nf][r] * ir);
    }
}

// ---------------- combine O0 - lam*O1, RMSNorm, -> bf16 (t, e) ----------------
__global__ __launch_bounds__(256)
void k_combine(const u16* __restrict__ O, const float* __restrict__ lamp,
               const float* __restrict__ subw, u16* __restrict__ Ab) {
    int gw = blockIdx.x * 4 + (threadIdx.x >> 6);  // 0..32767
    int lane = threadIdx.x & 63;
    int h = gw >> 11;
    int t = gw & 2047;
    float lam = *lamp;
    const u16* o0 = O + ((size_t)((2 * h) * 2048 + t)) * 128 + lane * 2;
    const u16* o1 = O + ((size_t)((2 * h + 1) * 2048 + t)) * 128 + lane * 2;
    unsigned int p0 = *(const unsigned int*)o0;
    unsigned int p1 = *(const unsigned int*)o1;
    float a0 = bf2f(p0 & 0xffffu) - lam * bf2f(p1 & 0xffffu);
    float a1 = bf2f(p0 >> 16) - lam * bf2f(p1 >> 16);
    float ss = a0 * a0 + a1 * a1;
    for (int m = 1; m < 64; m <<= 1) ss += __shfl_xor(ss, m);
    float inv = rsqrtf(ss * (1.f / 128.f) + 1e-5f) * (1.f - LAMBDA_INIT);
    a0 *= inv * subw[lane * 2];
    a1 *= inv * subw[lane * 2 + 1];
    unsigned int pk = (unsigned int)f2bf(a0) | ((unsigned int)f2bf(a1) << 16);
    *(unsigned int*)(Ab + (size_t)t * 2048 + h * 128 + lane * 2) = pk;
}

extern "C" void kernel_launch(void* const* d_in, const int* in_sizes, int n_in,
                              void* d_out, int out_size, void* d_ws, size_t ws_size,
                              hipStream_t stream) {
    const float* x    = (const float*)d_in[0];
    const float* Wq   = (const float*)d_in[2];
    const float* Wk   = (const float*)d_in[3];
    const float* Wv   = (const float*)d_in[4];
    const float* Wo   = (const float*)d_in[5];
    const float* lq1  = (const float*)d_in[6];
    const float* lk1  = (const float*)d_in[7];
    const float* lq2  = (const float*)d_in[8];
    const float* lk2  = (const float*)d_in[9];
    const float* subw = (const float*)d_in[10];
    float* out = (float*)d_out;

    char* ws = (char*)d_ws;
    size_t off = 0;
    auto alloc = [&](size_t sz) -> char* {
        char* p = ws + off;
        off = (off + sz + 255) & ~(size_t)255;
        return p;
    };
    float* lam  = (float*)alloc(4);
    float* cost = (float*)alloc((size_t)T_SEQ * 32 * 4);
    float* sint = (float*)alloc((size_t)T_SEQ * 32 * 4);
    u16* xbf   = (u16*)alloc((size_t)T_SEQ * EMB * 2);
    u16* wqkt  = (u16*)alloc((size_t)2 * EMB * EMB * 2);   // wqt | wkt contiguous
    u16* wvt   = (u16*)alloc((size_t)EMB * EMB * 2);
    u16* wot   = (u16*)alloc((size_t)EMB * EMB * 2);
    u16* qkbuf = (u16*)alloc((size_t)2 * G32 * T_SEQ * DH * 2);  // qbf | kbf
    u16* vtb   = (u16*)alloc((size_t)NHEAD * DV * T_SEQ * 2);
    u16* Obuf  = (u16*)alloc((size_t)G32 * T_SEQ * DV * 2);
    u16* Abf   = (u16*)alloc((size_t)T_SEQ * EMB * 2);
    float* parts = (float*)alloc((size_t)2 * EMB * EMB * 4);     // split-K partials
    u16* wqt = wqkt;
    u16* wkt = wqkt + (size_t)EMB * EMB;
    u16* qbf = qkbuf;
    u16* kbf = qkbuf + (size_t)G32 * T_SEQ * DH;

    k_lambda<<<1, 64, 0, stream>>>(lq1, lk1, lq2, lk2, lam);
    k_ropetab<<<256, 256, 0, stream>>>(cost, sint);
    k_cvt_x<<<4096, 256, 0, stream>>>(x, xbf);
    dim3 tg(64, 64);
    k_transpose_cvt<<<tg, 256, 0, stream>>>(Wq, wqt);
    k_transpose_cvt<<<tg, 256, 0, stream>>>(Wk, wkt);
    k_transpose_cvt<<<tg, 256, 0, stream>>>(Wv, wvt);
    k_transpose_cvt<<<tg, 256, 0, stream>>>(Wo, wot);
    // fused Q|K projection (N=4096), rope epilogue
    k_gemm<1><<<dim3(32, 16), 256, 0, stream>>>(xbf, wqkt, nullptr, qkbuf, cost, sint);
    // V^T = wvt @ xbf^T, split-K=2
    k_gemm<0><<<dim3(16, 16, 2), 256, 0, stream>>>(wvt, xbf, parts, nullptr, nullptr, nullptr);
    k_vadd<<<4096, 256, 0, stream>>>(parts, vtb);
    k_flash<<<1024, 256, 0, stream>>>(qbf, kbf, vtb, Obuf);
    k_combine<<<8192, 256, 0, stream>>>(Obuf, lam, subw, Abf);
    // out projection, split-K=2
    k_gemm<0><<<dim3(16, 16, 2), 256, 0, stream>>>(Abf, wot, parts, nullptr, nullptr, nullptr);
    k_oadd<<<4096, 256, 0, stream>>>(parts, out);
}